// Round 4
// baseline (195.549 us; speedup 1.0000x reference)
//
#include <hip/hip_runtime.h>

#define NF 36
#define QN 100
#define TN 20
#define CN 92
#define NB 64
#define BSTR 112   // ben/price row pad; [100..111] are -INF / 0 sentinels

// top-3 insert of value VV (index IDX) into (v0,i0 | v1,i1 | v2,i2), v0>=v1>=v2.
// med3 identities give exact shifted values; strict '>' keeps lowest q on ties.
#define SCAN3(VV, IDX) do { \
    float v_ = (VV); \
    bool c0_ = v_ > v0; \
    bool c1_ = v_ > v1; \
    bool c2_ = v_ > v2; \
    i2 = c1_ ? i1 : (c2_ ? (IDX) : i2); \
    v2 = __builtin_amdgcn_fmed3f(v_, v1, v2); \
    i1 = c0_ ? i0 : (c1_ ? (IDX) : i1); \
    v1 = __builtin_amdgcn_fmed3f(v_, v0, v1); \
    i0 = c0_ ? (IDX) : i0; \
    v0 = fmaxf(v0, v_); } while (0)

// descending compare-swap of (v,i,b,p) quads; order = (value desc, lower index first)
#define CSWAP(VA,IA,BA,PA, VB,IB,BB,PB) do { \
    bool sw_ = ((VB) > (VA)) || (((VB) == (VA)) && ((IB) < (IA))); \
    float tv_ = sw_ ? (VB) : (VA); float uv_ = sw_ ? (VA) : (VB); (VA) = tv_; (VB) = uv_; \
    int   ti_ = sw_ ? (IB) : (IA); int   ui_ = sw_ ? (IA) : (IB); (IA) = ti_; (IB) = ui_; \
    float tb_ = sw_ ? (BB) : (BA); float ub_ = sw_ ? (BA) : (BB); (BA) = tb_; (BB) = ub_; \
    float tp_ = sw_ ? (PB) : (PA); float up_ = sw_ ? (PA) : (PB); (PA) = tp_; (PB) = up_; \
} while (0)

__global__ __launch_bounds__(64, 3) void matcher_kernel(
    const float* __restrict__ logits,   // [64][3600][92]
    const float* __restrict__ pboxes,   // [64][3600][4]
    const int*   __restrict__ tlabels,  // [36][64][20]
    const float* __restrict__ tboxes,   // [36][64][20][4]
    float* __restrict__ out_cost,       // [64][36][100][20]
    float* __restrict__ out_pred,       // [64][36][20]
    float* __restrict__ out_tgt)        // [64][36][20]
{
    const int bf = blockIdx.x;          // b*36 + f
    const int b  = bf / NF;
    const int f  = bf % NF;
    const int lane = threadIdx.x;

    __shared__ __align__(16) float ben[TN][BSTR];   // benefit[t][q] = -cost[q][t]
    __shared__ __align__(16) float price[BSTR];
    __shared__ int   objl[TN];
    __shared__ int   slab[TN];
    __shared__ float tbr[TN][4];        // raw cxcywh
    __shared__ float tbx[TN][4];        // xyxy
    __shared__ float tarea[TN];

    // ---- stage targets ----
    if (lane < TN) {
        const int base = (f * NB + b) * TN + lane;
        slab[lane] = tlabels[base];
        const float* tb = tboxes + (size_t)base * 4;
        float cx = tb[0], cy = tb[1], w = tb[2], h = tb[3];
        tbr[lane][0] = cx; tbr[lane][1] = cy; tbr[lane][2] = w; tbr[lane][3] = h;
        float x1 = cx - 0.5f * w, y1 = cy - 0.5f * h;
        float x2 = cx + 0.5f * w, y2 = cy + 0.5f * h;
        tbx[lane][0] = x1; tbx[lane][1] = y1; tbx[lane][2] = x2; tbx[lane][3] = y2;
        tarea[lane] = (x2 - x1) * (y2 - y1);
    }
    __syncthreads();

    // ---- cost phase: register-resident logits (VGPR budget now 170), unchanged numerics ----
    float mn = INFINITY, mx = -INFINITY;
    for (int p = 0; p < 2; ++p) {
        const int q = lane + 64 * p;
        if (q < QN) {
            const size_t row = (size_t)b * (NF * QN) + (size_t)f * QN + q;
            const float* L = logits + row * CN;
            const float4* L4 = reinterpret_cast<const float4*>(L);
            float4 r[23];
            #pragma unroll
            for (int i = 0; i < 23; ++i) r[i] = L4[i];
            float m = -INFINITY;
            #pragma unroll
            for (int i = 0; i < 23; ++i) {
                float4 v = r[i];
                m = fmaxf(m, v.x); m = fmaxf(m, v.y); m = fmaxf(m, v.z); m = fmaxf(m, v.w);
            }
            float s = 0.f;
            #pragma unroll
            for (int i = 0; i < 23; ++i) {
                float4 v = r[i];
                s += expf(v.x - m); s += expf(v.y - m); s += expf(v.z - m); s += expf(v.w - m);
            }

            float4 pbv = reinterpret_cast<const float4*>(pboxes)[row];
            float cx = pbv.x, cy = pbv.y, w = pbv.z, h = pbv.w;
            float px1 = cx - 0.5f * w, py1 = cy - 0.5f * h;
            float px2 = cx + 0.5f * w, py2 = cy + 0.5f * h;
            float a1 = (px2 - px1) * (py2 - py1);

            for (int t = 0; t < TN; ++t) {
                float pc = expf(L[slab[t]] - m) / s;   // L1/L2-warm gather
                float cb = fabsf(cx - tbr[t][0]) + fabsf(cy - tbr[t][1]);
                cb = cb + fabsf(w - tbr[t][2]);
                cb = cb + fabsf(h - tbr[t][3]);
                float ltx = fmaxf(px1, tbx[t][0]), lty = fmaxf(py1, tbx[t][1]);
                float rbx = fminf(px2, tbx[t][2]), rby = fminf(py2, tbx[t][3]);
                float wx = fmaxf(rbx - ltx, 0.f), wy = fmaxf(rby - lty, 0.f);
                float inter = wx * wy;
                float uni = a1 + tarea[t] - inter;
                float iou = inter / uni;
                float ex1 = fminf(px1, tbx[t][0]), ey1 = fminf(py1, tbx[t][1]);
                float ex2 = fmaxf(px2, tbx[t][2]), ey2 = fmaxf(py2, tbx[t][3]);
                float ew = fmaxf(ex2 - ex1, 0.f), eh = fmaxf(ey2 - ey1, 0.f);
                float ae = ew * eh;
                float giou = iou - (ae - uni) / ae;
                float cost = (-pc) + 5.0f * cb - 2.0f * giou;
                ben[t][q] = -cost;
                mn = fminf(mn, cost);
                mx = fmaxf(mx, cost);
            }
        }
    }

    // init price + sentinels
    for (int i = lane; i < BSTR; i += 64) price[i] = 0.f;
    if (lane < TN) {
        float4 ninf; ninf.x = ninf.y = ninf.z = ninf.w = -INFINITY;
        float4* sp = reinterpret_cast<float4*>(&ben[lane][100]);   // 400B offset, 16B aligned
        sp[0] = ninf; sp[1] = ninf; sp[2] = ninf;                  // q = 100..111
    }
    __syncthreads();

    // eps (exact: spread = (-mn)-(-mx)+1e-6, /1000) — min/max exact under any order
    #pragma unroll
    for (int off = 32; off > 0; off >>= 1) {
        mn = fminf(mn, __shfl_xor(mn, off, 64));
        mx = fmaxf(mx, __shfl_xor(mx, off, 64));
    }
    const float eps = (((-mn) - (-mx)) + 1e-6f) / 1000.0f;

    // coalesced cost write-out from LDS
    {
        float4* dst = reinterpret_cast<float4*>(out_cost + (size_t)bf * (QN * TN));
        for (int i = lane; i < (QN * TN) / 4; i += 64) {
            int k = i * 4;
            int q = k / TN, t0 = k - q * TN;   // 20%4==0: never spans q
            float4 v;
            v.x = -ben[t0 + 0][q]; v.y = -ben[t0 + 1][q];
            v.z = -ben[t0 + 2][q]; v.w = -ben[t0 + 3][q];
            dst[i] = v;
        }
    }

    // ---- lane roles: lane = t*3 + j, scan chunks q0 = 0/36/72 (16B-aligned) ----
    const int myt = lane / 3;                       // 20,21 for lanes 60..63 (spectators)
    const int jj  = lane - myt * 3;
    const int q0  = jj * 36;                        // scan reads up to 107 < BSTR
    const bool is_leader = (lane < 60) && (jj == 0);
    float4 breg4[9];                                // my ben chunk, register-resident
    {
        const int tt = (lane < 60) ? myt : 0;
        const float4* bp = reinterpret_cast<const float4*>(&ben[tt][q0]);
        #pragma unroll
        for (int k = 0; k < 9; ++k) breg4[k] = bp[k];
    }
    int myobj = -1;

    // cached top-3 (leader state; semantics proven in R3). cval => bid bit-exact vs rescan.
    //   cv_j = ben[ci_j]-price[ci_j] (current bits), cb_j = ben[ci_j], cp_j = price[ci_j],
    //   cB = v2 at build time: bound on all unwatched values forever (prices only rise).
    float cv0 = 0.f, cv1 = 0.f, cv2 = 0.f;
    float cb0 = 0.f, cb1 = 0.f, cb2 = 0.f;
    float cp0 = 0.f, cp1 = 0.f, cp2 = 0.f, cB = 0.f;
    int ci0 = 0, ci1 = 0, ci2 = 0;
    bool cval = false;

    // ---- auction: Jacobi, exact reference dynamics, single wave, zero barriers,
    //      zero per-iteration LDS reads (all comms via ballot + v_readlane) ----
    for (int it = 0; it < 20000; ++it) {
        unsigned long long U = __ballot(is_leader && (myobj < 0));   // bits at 3t
        if (U == 0ull) break;
        unsigned long long R = __ballot(is_leader && (myobj < 0) && !cval);

        // rescan for triples whose leader bit is in R (3-lane split, LDS price + reg ben)
        if (R != 0ull) {
            const bool doscan = (lane < 60) && (((R >> (3 * myt)) & 1ull) != 0ull);
            float v0 = -INFINITY, v1 = -INFINITY, v2 = -INFINITY;
            int i0 = q0, i1 = q0, i2 = q0;
            if (doscan) {
                const float4* pp = reinterpret_cast<const float4*>(&price[q0]);
                #pragma unroll
                for (int k = 0; k < 9; ++k) {
                    float4 bv = breg4[k];
                    float4 pv = pp[k];                  // ds_read_b128
                    SCAN3(bv.x - pv.x, q0 + 4*k + 0);
                    SCAN3(bv.y - pv.y, q0 + 4*k + 1);
                    SCAN3(bv.z - pv.z, q0 + 4*k + 2);
                    SCAN3(bv.w - pv.w, q0 + 4*k + 3);
                }
            }
            // gather neighbor-chunk top-3s (lanes 3t+1, 3t+2) to the leader
            float sav0 = __shfl_down(v0, 1), sav1 = __shfl_down(v1, 1), sav2 = __shfl_down(v2, 1);
            int   sai0 = __shfl_down(i0, 1), sai1 = __shfl_down(i1, 1), sai2 = __shfl_down(i2, 1);
            float sbv0 = __shfl_down(v0, 2), sbv1 = __shfl_down(v1, 2), sbv2 = __shfl_down(v2, 2);
            int   sbi0 = __shfl_down(i0, 2), sbi1 = __shfl_down(i1, 2), sbi2 = __shfl_down(i2, 2);
            if (is_leader && (((R >> lane) & 1ull) != 0ull)) {
                // ordered inserts: ascending q across chunks + strict '>' = global tie rule
                SCAN3(sav0, sai0); SCAN3(sav1, sai1); SCAN3(sav2, sai2);
                SCAN3(sbv0, sbi0); SCAN3(sbv1, sbi1); SCAN3(sbv2, sbi2);
                ci0 = i0; ci1 = i1; ci2 = i2;
                cv0 = v0; cv1 = v1; cv2 = v2; cB = v2;
                cb0 = ben[myt][ci0]; cb1 = ben[myt][ci1]; cb2 = ben[myt][ci2];
                cp0 = price[ci0];    cp1 = price[ci1];    cp2 = price[ci2];
                cval = true;
            }
        }

        // bid from cache (active implies cval: R-pass just refreshed it)
        const bool active = is_leader && (myobj < 0);
        const float mybid  = cp0 + (cv0 - cv1) + eps;   // exact ref op order
        const int   mybidq = ci0;

        // single register-broadcast pass over all bidders: resolution + eviction + cache upkeep
        bool lose = false, ev = false, anyhit = false;
        float np0 = cp0, np1 = cp1, np2 = cp2;
        {
            unsigned long long uu = U;                   // wave-uniform loop
            while (uu) {
                const int pos = (int)__builtin_ctzll(uu); uu &= uu - 1ull;
                const int t2  = pos / 3;
                const int   q2 = __builtin_amdgcn_readlane(mybidq, pos);
                const float f2 = __int_as_float(__builtin_amdgcn_readlane(__float_as_int(mybid), pos));
                // resolution: max bid wins, min-t on ties (self-compare harmlessly false)
                lose = lose || ((q2 == mybidq) && ((f2 > mybid) || ((f2 == mybid) && (t2 < myt))));
                // eviction: any bid on my object always displaces me (a winner always exists)
                ev = ev || (q2 == myobj);
                // cache upkeep: new price[q] = max of bids on q (losing bids absorbed by fmax)
                bool g0 = (q2 == ci0), g1 = (q2 == ci1), g2 = (q2 == ci2);
                np0 = g0 ? fmaxf(np0, f2) : np0;
                np1 = g1 ? fmaxf(np1, f2) : np1;
                np2 = g2 ? fmaxf(np2, f2) : np2;
                anyhit = anyhit || g0 || g1 || g2;
            }
        }
        if (active && !lose) {                          // winners have distinct q
            myobj = mybidq;
            price[mybidq] = mybid;                      // ds_write; read only at rescans
        } else if (ev) {
            myobj = -1;                                 // evicted owner (cache kept+maintained)
        }
        if (cval && anyhit) {
            cp0 = np0; cp1 = np1; cp2 = np2;
            cv0 = cb0 - cp0; cv1 = cb1 - cp1; cv2 = cb2 - cp2;   // single sub == rescan bits
            CSWAP(cv0,ci0,cb0,cp0, cv1,ci1,cb1,cp1);
            CSWAP(cv1,ci1,cb1,cp1, cv2,ci2,cb2,cp2);
            CSWAP(cv0,ci0,cb0,cp0, cv1,ci1,cb1,cp1);
            // unwatched stay <= cB forever: top index exact iff cv0 > cB,
            // second VALUE exact iff cv1 >= cB (equality: value ties don't affect the bid)
            cval = (cv0 > cB) && (cv1 >= cB);
        }
    }
    __syncthreads();
    if (is_leader) objl[myt] = myobj;
    __syncthreads();

    // ---- stable argsort of obj_of (rank computation) ----
    if (lane < TN) {
        int v = objl[lane];
        int r = 0;
        for (int u2 = 0; u2 < TN; ++u2) {
            int w = objl[u2];
            r += (w < v) || (w == v && u2 < lane);
        }
        out_pred[(size_t)bf * TN + r] = (float)v;
        out_tgt[(size_t)bf * TN + r]  = (float)lane;
    }
}

extern "C" void kernel_launch(void* const* d_in, const int* in_sizes, int n_in,
                              void* d_out, int out_size, void* d_ws, size_t ws_size,
                              hipStream_t stream) {
    const float* logits  = (const float*)d_in[0];
    const float* pboxes  = (const float*)d_in[1];
    const int*   tlabels = (const int*)d_in[2];
    const float* tboxes  = (const float*)d_in[3];

    float* out = (float*)d_out;
    float* out_cost = out;                                   // 64*36*100*20
    float* out_pred = out + (size_t)NB * NF * QN * TN;       // 64*36*20
    float* out_tgt  = out_pred + (size_t)NB * NF * TN;       // 64*36*20

    hipLaunchKernelGGL(matcher_kernel, dim3(NB * NF), dim3(64), 0, stream,
                       logits, pboxes, tlabels, tboxes, out_cost, out_pred, out_tgt);
}

// Round 5
// 176.571 us; speedup vs baseline: 1.1075x; 1.1075x over previous
//
#include <hip/hip_runtime.h>

#define NF 36
#define QN 100
#define TN 20
#define CN 92
#define NB 64
#define BSTR 112   // ben/price row pad; [100..111] are -INF / 0 sentinels

// one element of the running top-2 scan; med3 is a pure selection identity:
// new v1 = median(v, v0, v1) given invariant v0 >= v1. Strict '>' keeps lowest q on ties.
#define TOP2_STEP(VV, IDX) do { \
    float v_ = (VV); bool c_ = v_ > v0; \
    float nv1_ = __builtin_amdgcn_fmed3f(v_, v0, v1); \
    i0 = c_ ? (IDX) : i0; v0 = fmaxf(v0, v_); v1 = nv1_; } while (0)

__global__ __launch_bounds__(64) void matcher_kernel(
    const float* __restrict__ logits,   // [64][3600][92]
    const float* __restrict__ pboxes,   // [64][3600][4]
    const int*   __restrict__ tlabels,  // [36][64][20]
    const float* __restrict__ tboxes,   // [36][64][20][4]
    float* __restrict__ out_cost,       // [64][36][100][20]
    float* __restrict__ out_pred,       // [64][36][20]
    float* __restrict__ out_tgt)        // [64][36][20]
{
    const int bf = blockIdx.x;          // b*36 + f
    const int b  = bf / NF;
    const int f  = bf % NF;
    const int lane = threadIdx.x;

    __shared__ __align__(16) float ben[TN][BSTR];   // benefit[t][q] = -cost[q][t]
    __shared__ __align__(16) float price[BSTR];
    __shared__ int   owner[QN];
    __shared__ int   bbmax[QN];         // best bid per object (float-as-int, bids > 0)
    __shared__ int   wmin[QN];          // min-t winner per object
    __shared__ int   evict[TN];
    __shared__ int   objl[TN];
    __shared__ int   slab[TN];
    __shared__ float tbr[TN][4];        // raw cxcywh
    __shared__ float tbx[TN][4];        // xyxy
    __shared__ float tarea[TN];

    // ---- stage targets ----
    if (lane < TN) {
        const int base = (f * NB + b) * TN + lane;
        slab[lane] = tlabels[base];
        const float* tb = tboxes + (size_t)base * 4;
        float cx = tb[0], cy = tb[1], w = tb[2], h = tb[3];
        tbr[lane][0] = cx; tbr[lane][1] = cy; tbr[lane][2] = w; tbr[lane][3] = h;
        float x1 = cx - 0.5f * w, y1 = cy - 0.5f * h;
        float x2 = cx + 0.5f * w, y2 = cy + 0.5f * h;
        tbx[lane][0] = x1; tbx[lane][1] = y1; tbx[lane][2] = x2; tbx[lane][3] = y2;
        tarea[lane] = (x2 - x1) * (y2 - y1);
        evict[lane] = 0;
    }
    __syncthreads();

    // ---- cost phase: ONLINE softmax (row streamed from HBM exactly once) +
    //      slab-gathers issued alongside the stream (L1-hot, register-resident) ----
    float mn = INFINITY, mx = -INFINITY;
    for (int p = 0; p < 2; ++p) {
        const int q = lane + 64 * p;
        if (q < QN) {
            const size_t row = (size_t)b * (NF * QN) + (size_t)f * QN + q;
            const float* L = logits + row * CN;
            const float4* L4 = reinterpret_cast<const float4*>(L);

            // issue the 20 class-gathers immediately: same cache lines as the stream,
            // all 43 loads in flight together; values land in registers.
            float g[TN];
            #pragma unroll
            for (int t = 0; t < TN; ++t) g[t] = L[slab[t]];

            // online max + exp-sum: single pass, ~2 live registers of state.
            // m is bit-exact (max is exact); s differs only in rounding association.
            float m = -INFINITY, s = 0.f;
            #pragma unroll
            for (int i = 0; i < 23; ++i) {
                float4 v = L4[i];
                float cm = fmaxf(fmaxf(v.x, v.y), fmaxf(v.z, v.w));
                float m2 = fmaxf(m, cm);
                s = s * expf(m - m2)
                  + expf(v.x - m2) + expf(v.y - m2)
                  + expf(v.z - m2) + expf(v.w - m2);
                m = m2;
            }

            float4 pbv = reinterpret_cast<const float4*>(pboxes)[row];
            float cx = pbv.x, cy = pbv.y, w = pbv.z, h = pbv.w;
            float px1 = cx - 0.5f * w, py1 = cy - 0.5f * h;
            float px2 = cx + 0.5f * w, py2 = cy + 0.5f * h;
            float a1 = (px2 - px1) * (py2 - py1);

            for (int t = 0; t < TN; ++t) {
                float pc = expf(g[t] - m) / s;         // register-resident gather
                float cb = fabsf(cx - tbr[t][0]) + fabsf(cy - tbr[t][1]);
                cb = cb + fabsf(w - tbr[t][2]);
                cb = cb + fabsf(h - tbr[t][3]);
                float ltx = fmaxf(px1, tbx[t][0]), lty = fmaxf(py1, tbx[t][1]);
                float rbx = fminf(px2, tbx[t][2]), rby = fminf(py2, tbx[t][3]);
                float wx = fmaxf(rbx - ltx, 0.f), wy = fmaxf(rby - lty, 0.f);
                float inter = wx * wy;
                float uni = a1 + tarea[t] - inter;
                float iou = inter / uni;
                float ex1 = fminf(px1, tbx[t][0]), ey1 = fminf(py1, tbx[t][1]);
                float ex2 = fmaxf(px2, tbx[t][2]), ey2 = fmaxf(py2, tbx[t][3]);
                float ew = fmaxf(ex2 - ex1, 0.f), eh = fmaxf(ey2 - ey1, 0.f);
                float ae = ew * eh;
                float giou = iou - (ae - uni) / ae;
                float cost = (-pc) + 5.0f * cb - 2.0f * giou;
                ben[t][q] = -cost;
                mn = fminf(mn, cost);
                mx = fmaxf(mx, cost);
            }
        }
    }

    // init price/owner + sentinels (before the barrier)
    for (int i = lane; i < BSTR; i += 64) price[i] = 0.f;
    for (int i = lane; i < QN; i += 64) owner[i] = -1;
    if (lane < TN) {
        float4 ninf; ninf.x = ninf.y = ninf.z = ninf.w = -INFINITY;
        float4* sp = reinterpret_cast<float4*>(&ben[lane][100]);   // 400B offset, 16B aligned
        sp[0] = ninf; sp[1] = ninf; sp[2] = ninf;                  // q = 100..111
    }
    __syncthreads();

    // eps (exact: spread = (-mn)-(-mx)+1e-6, /1000) — min/max exact under any order
    #pragma unroll
    for (int off = 32; off > 0; off >>= 1) {
        mn = fminf(mn, __shfl_xor(mn, off, 64));
        mx = fmaxf(mx, __shfl_xor(mx, off, 64));
    }
    const float eps = (((-mn) - (-mx)) + 1e-6f) / 1000.0f;

    // coalesced cost write-out from LDS
    {
        float4* dst = reinterpret_cast<float4*>(out_cost + (size_t)bf * (QN * TN));
        for (int i = lane; i < (QN * TN) / 4; i += 64) {
            int k = i * 4;
            int q = k / TN, t0 = k - q * TN;   // 20%4==0: never spans q
            float4 v;
            v.x = -ben[t0 + 0][q]; v.y = -ben[t0 + 1][q];
            v.z = -ben[t0 + 2][q]; v.w = -ben[t0 + 3][q];
            dst[i] = v;
        }
    }

    // ---- benefit chunk -> registers: lane = t*3 + j, chunks q0 = 0/36/72 (16B-aligned) ----
    const int myt = lane / 3;                       // 20,21 for lanes 60..63 (spectators)
    const int jj  = lane - myt * 3;
    const int q0  = jj * 36;                        // scan reads up to 107 < BSTR
    const bool is_leader = (lane < 60) && (jj == 0);
    float4 breg4[9];
    {
        const int tt = (lane < 60) ? myt : 0;
        const float4* bp = reinterpret_cast<const float4*>(&ben[tt][q0]);
        #pragma unroll
        for (int k = 0; k < 9; ++k) breg4[k] = bp[k];
    }
    int myobj = -1;

    // ---- auction: Jacobi, exact reference dynamics, single-wave (R1 verbatim) ----
    for (int it = 0; it < 20000; ++it) {
        unsigned long long U = __ballot(is_leader && (myobj < 0));  // bits at 3t
        if (U == 0ull) break;
        const int u = __popcll(U);                  // wave-uniform

        int bidq = 0; float bidf = 0.f;             // per-leader bid target / value
        if (u > 2) {
            // heavy path: 3 lanes/bidder, 36-wide chunks, vector LDS price reads
            float v0 = -INFINITY, v1 = -INFINITY; int i0 = q0;
            const float4* pp = reinterpret_cast<const float4*>(&price[q0]);
            #pragma unroll
            for (int k = 0; k < 9; ++k) {
                float4 bv = breg4[k];
                float4 pv = pp[k];                  // ds_read_b128
                TOP2_STEP(bv.x - pv.x, q0 + 4*k + 0);
                TOP2_STEP(bv.y - pv.y, q0 + 4*k + 1);
                TOP2_STEP(bv.z - pv.z, q0 + 4*k + 2);
                TOP2_STEP(bv.w - pv.w, q0 + 4*k + 3);
            }
            // ordered 3-way merge (ascending q0 with lane: strict '>' keeps lowest q)
            {
                float av0 = __shfl_down(v0, 1), av1 = __shfl_down(v1, 1);
                int   ai0 = __shfl_down(i0, 1);
                float bv0 = __shfl_down(v0, 2), bv1 = __shfl_down(v1, 2);
                int   bi0 = __shfl_down(i0, 2);
                if (av0 > v0) { v1 = fmaxf(v0, av1); v0 = av0; i0 = ai0; }
                else          { v1 = fmaxf(av0, v1); }
                if (bv0 > v0) { v1 = fmaxf(v0, bv1); v0 = bv0; i0 = bi0; }
                else          { v1 = fmaxf(bv0, v1); }
            }
            bidq = i0;
            bidf = price[i0] + (v0 - v1) + eps;     // exact ref op order
        } else {
            // light path: u in {1,2}; 32 lanes/bidder, 4-element chunks + butterfly merge
            const int ta = (int)__builtin_ctzll(U) / 3;
            const int tb = (u == 2) ? (int)__builtin_ctzll(U & (U - 1ull)) / 3 : ta;
            const int grp = lane >> 5;
            const int tg  = grp ? tb : ta;
            const int l   = lane & 31;
            const int lc  = (l > 25) ? 25 : l;      // l>=25 reads -INF sentinels
            const int qb  = lc * 4;
            float4 bv = *reinterpret_cast<const float4*>(&ben[tg][qb]);
            float4 pv = *reinterpret_cast<const float4*>(&price[qb]);
            float v0 = -INFINITY, v1 = -INFINITY; int i0 = qb;
            TOP2_STEP(bv.x - pv.x, qb + 0);
            TOP2_STEP(bv.y - pv.y, qb + 1);
            TOP2_STEP(bv.z - pv.z, qb + 2);
            TOP2_STEP(bv.w - pv.w, qb + 3);
            // butterfly within each 32-lane group; total order (value, then lower q)
            #pragma unroll
            for (int s = 16; s >= 1; s >>= 1) {
                float av0 = __shfl_xor(v0, s), av1 = __shfl_xor(v1, s);
                int   ai0 = __shfl_xor(i0, s);
                bool take = (av0 > v0) || (av0 == v0 && ai0 < i0);
                float nv1 = take ? fmaxf(v0, av1) : fmaxf(v1, av0);
                v0 = take ? av0 : v0;
                i0 = take ? ai0 : i0;
                v1 = nv1;
            }
            float bidg = price[i0] + (v0 - v1) + eps;
            // route each group's result to its canonical leader lane (3*t)
            float b0 = __shfl(bidg, 0),  b1 = __shfl(bidg, 32);
            int   i0a = __shfl(i0, 0),   i0b = __shfl(i0, 32);
            if (lane == 3 * ta)            { bidq = i0a; bidf = b0; }
            if (u == 2 && lane == 3 * tb)  { bidq = i0b; bidf = b1; }
        }

        // ---- resolution: best_bid=max per object (atomicMax on positive-float-as-int,
        //      bit-exact), winner = min-t among bid >= max (atomicMin) — identical to ref ----
        const bool act = is_leader && (myobj < 0);
        bool win = false;
        if (u == 1) {
            win = act;                               // lone bidder always wins
        } else {
            if (act) { bbmax[bidq] = 0; wmin[bidq] = 64; }   // bids > 0, so 0 == -inf
            __syncthreads();
            if (act) atomicMax(&bbmax[bidq], __float_as_int(bidf));
            __syncthreads();
            bool cand = false;
            if (act) {
                cand = (__float_as_int(bidf) >= bbmax[bidq]);
                if (cand) atomicMin(&wmin[bidq], myt);
            }
            __syncthreads();
            win = cand && (wmin[bidq] == myt);
        }
        if (win) {                                   // winners have distinct q
            int old = owner[bidq];
            owner[bidq] = myt;
            price[bidq] = bidf;
            myobj = bidq;
            if (old >= 0) evict[old] = 1;            // evictees disjoint from winners
        }
        __syncthreads();
        if (is_leader && evict[myt]) { myobj = -1; evict[myt] = 0; }
    }
    __syncthreads();
    if (is_leader) objl[myt] = myobj;
    __syncthreads();

    // ---- stable argsort of obj_of (rank computation) ----
    if (lane < TN) {
        int v = objl[lane];
        int r = 0;
        for (int u2 = 0; u2 < TN; ++u2) {
            int w = objl[u2];
            r += (w < v) || (w == v && u2 < lane);
        }
        out_pred[(size_t)bf * TN + r] = (float)v;
        out_tgt[(size_t)bf * TN + r]  = (float)lane;
    }
}

extern "C" void kernel_launch(void* const* d_in, const int* in_sizes, int n_in,
                              void* d_out, int out_size, void* d_ws, size_t ws_size,
                              hipStream_t stream) {
    const float* logits  = (const float*)d_in[0];
    const float* pboxes  = (const float*)d_in[1];
    const int*   tlabels = (const int*)d_in[2];
    const float* tboxes  = (const float*)d_in[3];

    float* out = (float*)d_out;
    float* out_cost = out;                                   // 64*36*100*20
    float* out_pred = out + (size_t)NB * NF * QN * TN;       // 64*36*20
    float* out_tgt  = out_pred + (size_t)NB * NF * TN;       // 64*36*20

    hipLaunchKernelGGL(matcher_kernel, dim3(NB * NF), dim3(64), 0, stream,
                       logits, pboxes, tlabels, tboxes, out_cost, out_pred, out_tgt);
}